// Round 3
// baseline (382.977 us; speedup 1.0000x reference)
//
#include <hip/hip_runtime.h>
#include <climits>

typedef __attribute__((ext_vector_type(8))) short s8;      // 8 bf16 = 4 VGPRs
typedef __attribute__((ext_vector_type(4))) float f32x4;   // MFMA acc

#define BQ    256
#define DDIM  256
#define NBANK 100000
#define BN    64                          // bank cols per block (4 col-tiles of 16)
#define NJB   ((NBANK + BN - 1) / BN)     // 1563
#define SENT  1e30f

// Split fp32 x into bf16 hi (round-half-up) + bf16 lo: x ~= hi + lo, |err| <~ 2^-18|x|
__device__ inline void splitElem(float x, s8& h, s8& l, int i) {
    unsigned u  = __float_as_uint(x);
    unsigned uh = (u + 0x8000u) & 0xFFFF0000u;     // rounded-to-16-bit
    h[i] = (short)(uh >> 16);
    float lf = x - __uint_as_float(uh);            // exact
    l[i] = (short)((__float_as_uint(lf) + 0x8000u) >> 16);
}

__device__ inline void split8(const float4 v0, const float4 v1, s8& h, s8& l) {
    splitElem(v0.x, h, l, 0); splitElem(v0.y, h, l, 1);
    splitElem(v0.z, h, l, 2); splitElem(v0.w, h, l, 3);
    splitElem(v1.x, h, l, 4); splitElem(v1.y, h, l, 5);
    splitElem(v1.z, h, l, 6); splitElem(v1.w, h, l, 7);
}

__device__ inline float sq8(const float4 v0, const float4 v1, float s) {
    s = fmaf(v0.x, v0.x, s); s = fmaf(v0.y, v0.y, s);
    s = fmaf(v0.z, v0.z, s); s = fmaf(v0.w, v0.w, s);
    s = fmaf(v1.x, v1.x, s); s = fmaf(v1.y, v1.y, s);
    s = fmaf(v1.z, v1.z, s); s = fmaf(v1.w, v1.w, s);
    return s;
}

// Kernel 1: MFMA GEMM (split-bf16) + fused masked partial argmin.
// 512 threads = 8 waves; wave w owns rows w*32..w*32+31 (A-frags in registers).
// B-frags loaded straight from global in MFMA lane layout; no LDS tiles.
__global__ __launch_bounds__(512, 2) void gemm_argmin_partial(
    const float* __restrict__ feature, const float* __restrict__ bank,
    const int* __restrict__ cluster_label, const int* __restrict__ class_label,
    const int* __restrict__ cluster_idx,  const int* __restrict__ gt_label,
    float* __restrict__ wsPV, int* __restrict__ wsPI,
    float* __restrict__ wsDV, int* __restrict__ wsDI)
{
    __shared__ int clsS[BN], cluS[BN], rowGt[BQ], rowClu[BQ];
    const int tid = threadIdx.x;
    const int jb  = blockIdx.x;
    const int j0  = jb * BN;

    if (tid < BN) {
        int jg = j0 + tid;
        int jc = jg < NBANK ? jg : NBANK - 1;
        clsS[tid] = class_label[jc];
        cluS[tid] = cluster_label[jc];
    }
    if (tid < BQ) { rowGt[tid] = gt_label[tid]; rowClu[tid] = cluster_idx[tid]; }
    __syncthreads();

    const int w = tid >> 6, lane = tid & 63;
    const int g = lane >> 4, c = lane & 15;   // g = k-octet / row-quad, c = row/col within tile

    // ---- A fragments: rows w*32 + rt*16 + c, k = ks*32 + g*8 + j  (m120-verified A layout)
    s8 aH[2][8], aL[2][8];
    #pragma unroll
    for (int rt = 0; rt < 2; ++rt) {
        const float* ap = feature + (size_t)(w * 32 + rt * 16 + c) * DDIM + g * 8;
        #pragma unroll
        for (int ks = 0; ks < 8; ++ks) {
            float4 v0 = *(const float4*)(ap + ks * 32);
            float4 v1 = *(const float4*)(ap + ks * 32 + 4);
            split8(v0, v1, aH[rt][ks], aL[rt][ks]);
        }
    }

    f32x4 acc[4][2];
    #pragma unroll
    for (int ct = 0; ct < 4; ++ct)
        #pragma unroll
        for (int rt = 0; rt < 2; ++rt)
            acc[ct][rt] = (f32x4){0.f, 0.f, 0.f, 0.f};
    float b2v[4] = {0.f, 0.f, 0.f, 0.f};

    const float* bp[4];
    #pragma unroll
    for (int ct = 0; ct < 4; ++ct) {
        int col = j0 + ct * 16 + c;
        col = col < NBANK ? col : NBANK - 1;
        bp[ct] = bank + (size_t)col * DDIM + g * 8;
    }

    // ---- main loop: 32 steps (ks 0..7 x ct 0..3), 1-deep B prefetch
    float4 cur0 = *(const float4*)(bp[0]);
    float4 cur1 = *(const float4*)(bp[0] + 4);
    #pragma unroll
    for (int i = 0; i < 32; ++i) {
        const int ks = i >> 2, ct = i & 3;
        float4 nx0, nx1;
        if (i < 31) {
            const float* p = bp[(i + 1) & 3] + ((i + 1) >> 2) * 32;
            nx0 = *(const float4*)p; nx1 = *(const float4*)(p + 4);
        }
        s8 bh, bl;
        split8(cur0, cur1, bh, bl);
        b2v[ct] = sq8(cur0, cur1, b2v[ct]);
        #pragma unroll
        for (int rt = 0; rt < 2; ++rt) {
            acc[ct][rt] = __builtin_amdgcn_mfma_f32_16x16x32_bf16(aH[rt][ks], bh, acc[ct][rt], 0, 0, 0);
            acc[ct][rt] = __builtin_amdgcn_mfma_f32_16x16x32_bf16(aH[rt][ks], bl, acc[ct][rt], 0, 0, 0);
            acc[ct][rt] = __builtin_amdgcn_mfma_f32_16x16x32_bf16(aL[rt][ks], bh, acc[ct][rt], 0, 0, 0);
            acc[ct][rt] = __builtin_amdgcn_mfma_f32_16x16x32_bf16(aL[rt][ks], bl, acc[ct][rt], 0, 0, 0);
        }
        if (i < 31) { cur0 = nx0; cur1 = nx1; }
    }

    // ---- ||b||^2: lane covers k-octets g*8 (+32*ks); sum the 4 g-groups (bitwise identical per group)
    #pragma unroll
    for (int ct = 0; ct < 4; ++ct) {
        b2v[ct] += __shfl_xor(b2v[ct], 16);
        b2v[ct] += __shfl_xor(b2v[ct], 32);
    }

    // ---- epilogue: C/D layout col = lane&15 (=c), row = g*4 + reg  (m89/m91-verified)
    #pragma unroll
    for (int rt = 0; rt < 2; ++rt) {
        #pragma unroll
        for (int r = 0; r < 4; ++r) {
            const int row  = w * 32 + rt * 16 + g * 4 + r;
            const int myGt = rowGt[row], myClu = rowClu[row];
            float bpv = SENT, bdv = SENT;
            int   bpi = INT_MAX, bdi = INT_MAX;
            #pragma unroll
            for (int ct = 0; ct < 4; ++ct) {   // ascending ct = ascending col per lane
                const int jg = j0 + ct * 16 + c;
                const float s = b2v[ct] - 2.f * acc[ct][rt][r];
                if (jg < NBANK && clsS[ct * 16 + c] != myGt) {
                    if (s < bdv) { bdv = s; bdi = jg; }
                    if (cluS[ct * 16 + c] == myClu && s < bpv) { bpv = s; bpi = jg; }
                }
            }
            // tie-aware reduce across the 16 lanes sharing this row (aligned 16-lane group)
            #pragma unroll
            for (int off = 1; off < 16; off <<= 1) {
                float vv = __shfl_xor(bpv, off); int ii = __shfl_xor(bpi, off);
                if (vv < bpv || (vv == bpv && ii < bpi)) { bpv = vv; bpi = ii; }
                vv = __shfl_xor(bdv, off); ii = __shfl_xor(bdi, off);
                if (vv < bdv || (vv == bdv && ii < bdi)) { bdv = vv; bdi = ii; }
            }
            if (c == 0) {
                const size_t o = (size_t)row * NJB + jb;
                wsPV[o] = bpv; wsPI[o] = bpi;
                wsDV[o] = bdv; wsDI[o] = bdi;
            }
        }
    }
}

// Kernel 2: per-row reduction over NJB partials, fallback select, gather bank row.
__global__ __launch_bounds__(256) void reduce_gather(
    const float* __restrict__ wsPV, const int* __restrict__ wsPI,
    const float* __restrict__ wsDV, const int* __restrict__ wsDI,
    const float* __restrict__ bank, float* __restrict__ out)
{
    const int row = blockIdx.x, tid = threadIdx.x;
    float bpv = SENT, bdv = SENT;
    int   bpi = INT_MAX, bdi = INT_MAX;
    for (int b = tid; b < NJB; b += 256) {
        float v = wsPV[(size_t)row * NJB + b]; int ix = wsPI[(size_t)row * NJB + b];
        if (v < bpv || (v == bpv && ix < bpi)) { bpv = v; bpi = ix; }
        v = wsDV[(size_t)row * NJB + b]; ix = wsDI[(size_t)row * NJB + b];
        if (v < bdv || (v == bdv && ix < bdi)) { bdv = v; bdi = ix; }
    }
    #pragma unroll
    for (int off = 32; off > 0; off >>= 1) {
        float v = __shfl_down(bpv, off); int ix = __shfl_down(bpi, off);
        if (v < bpv || (v == bpv && ix < bpi)) { bpv = v; bpi = ix; }
        v = __shfl_down(bdv, off); ix = __shfl_down(bdi, off);
        if (v < bdv || (v == bdv && ix < bdi)) { bdv = v; bdi = ix; }
    }
    __shared__ float swPV[4], swDV[4];
    __shared__ int   swPI[4], swDI[4];
    __shared__ int   sIdx;
    const int lane = tid & 63, wv = tid >> 6;
    if (lane == 0) { swPV[wv] = bpv; swPI[wv] = bpi; swDV[wv] = bdv; swDI[wv] = bdi; }
    __syncthreads();
    if (tid == 0) {
        float pv = swPV[0]; int pi = swPI[0];
        float dv = swDV[0]; int di = swDI[0];
        #pragma unroll
        for (int w = 1; w < 4; ++w) {
            if (swPV[w] < pv || (swPV[w] == pv && swPI[w] < pi)) { pv = swPV[w]; pi = swPI[w]; }
            if (swDV[w] < dv || (swDV[w] == dv && swDI[w] < di)) { dv = swDV[w]; di = swDI[w]; }
        }
        sIdx = (pi != INT_MAX) ? pi : ((di != INT_MAX) ? di : 0);
    }
    __syncthreads();
    out[row * DDIM + tid] = bank[(size_t)sIdx * DDIM + tid];
}

extern "C" void kernel_launch(void* const* d_in, const int* in_sizes, int n_in,
                              void* d_out, int out_size, void* d_ws, size_t ws_size,
                              hipStream_t stream) {
    const float* feature       = (const float*)d_in[0];
    const float* bank          = (const float*)d_in[1];
    const int*   cluster_label = (const int*)d_in[2];
    const int*   class_label   = (const int*)d_in[3];
    const int*   cluster_idx   = (const int*)d_in[4];
    const int*   gt_label      = (const int*)d_in[5];
    float* out = (float*)d_out;

    // Workspace: 4 arrays of [256][NJB] = 6.4 MB
    const size_t per = (size_t)BQ * NJB;
    float* wsPV = (float*)d_ws;
    int*   wsPI = (int*)d_ws + per;
    float* wsDV = (float*)d_ws + 2 * per;
    int*   wsDI = (int*)d_ws + 3 * per;

    hipLaunchKernelGGL(gemm_argmin_partial, dim3(NJB), dim3(512), 0, stream,
                       feature, bank, cluster_label, class_label, cluster_idx, gt_label,
                       wsPV, wsPI, wsDV, wsDI);
    hipLaunchKernelGGL(reduce_gather, dim3(BQ), dim3(256), 0, stream,
                       wsPV, wsPI, wsDV, wsDI, bank, out);
}

// Round 4
// 239.907 us; speedup vs baseline: 1.5964x; 1.5964x over previous
//
#include <hip/hip_runtime.h>
#include <climits>

typedef __attribute__((ext_vector_type(8))) short s8;      // 8 bf16 = 4 VGPRs
typedef __attribute__((ext_vector_type(4))) float f32x4;   // MFMA acc

#define BQ    256
#define DDIM  256
#define NBANK 100000
#define BN    64                          // bank cols per block (4 col-tiles of 16)
#define NJB   ((NBANK + BN - 1) / BN)     // 1563
#define SENT  1e30f

// Split fp32 x into bf16 hi (round-half-up) + bf16 lo: x ~= hi + lo, |err| <~ 2^-18|x|
__device__ inline void splitElem(float x, s8& h, s8& l, int i) {
    unsigned u  = __float_as_uint(x);
    unsigned uh = (u + 0x8000u) & 0xFFFF0000u;
    h[i] = (short)(uh >> 16);
    float lf = x - __uint_as_float(uh);            // exact
    l[i] = (short)((__float_as_uint(lf) + 0x8000u) >> 16);
}

__device__ inline void split8(const float4 v0, const float4 v1, s8& h, s8& l) {
    splitElem(v0.x, h, l, 0); splitElem(v0.y, h, l, 1);
    splitElem(v0.z, h, l, 2); splitElem(v0.w, h, l, 3);
    splitElem(v1.x, h, l, 4); splitElem(v1.y, h, l, 5);
    splitElem(v1.z, h, l, 6); splitElem(v1.w, h, l, 7);
}

__device__ inline float sq8(const float4 v0, const float4 v1, float s) {
    s = fmaf(v0.x, v0.x, s); s = fmaf(v0.y, v0.y, s);
    s = fmaf(v0.z, v0.z, s); s = fmaf(v0.w, v0.w, s);
    s = fmaf(v1.x, v1.x, s); s = fmaf(v1.y, v1.y, s);
    s = fmaf(v1.z, v1.z, s); s = fmaf(v1.w, v1.w, s);
    return s;
}

// Kernel 0: pre-split the tiny A (feature) into MFMA-A-fragment-ordered bf16 hi/lo.
// Frag t = (rowtile rt)*8 + ks, lane l holds feature[rt*16+(l&15)][ks*32+(l>>4)*8 + 0..7].
__global__ __launch_bounds__(512) void split_feature(
    const float* __restrict__ feature, s8* __restrict__ fH, s8* __restrict__ fL)
{
    const int t    = blockIdx.x * 512 + threadIdx.x;   // 0..8191
    const int lane = t & 63, ks = (t >> 6) & 7, rt = t >> 9;
    const int row  = rt * 16 + (lane & 15);
    const int k0   = ks * 32 + (lane >> 4) * 8;
    const float* p = feature + (size_t)row * DDIM + k0;
    const float4 v0 = *(const float4*)p;
    const float4 v1 = *(const float4*)(p + 4);
    s8 h, l;
    split8(v0, v1, h, l);
    fH[t] = h; fL[t] = l;
}

// Kernel 1: split-bf16 MFMA GEMM + fused masked partial argmin.
// 256 threads = 4 waves; wave w owns rows w*64..+63 (4 row-tiles). B staged per
// k-slice: fp32 -> split -> LDS in fragment layout, once per bank element total.
__global__ __launch_bounds__(256, 3) void gemm_argmin_partial(
    const s8* __restrict__ fH, const s8* __restrict__ fL,
    const float* __restrict__ bank,
    const int* __restrict__ cluster_label, const int* __restrict__ class_label,
    const int* __restrict__ cluster_idx,  const int* __restrict__ gt_label,
    float* __restrict__ wsPV, int* __restrict__ wsPI,
    float* __restrict__ wsDV, int* __restrict__ wsDI)
{
    __shared__ __align__(16) s8 bHs[4 * 64];   // [ct][lane] 4 KB
    __shared__ __align__(16) s8 bLs[4 * 64];   // 4 KB
    __shared__ float b2s[BN];
    __shared__ int clsS[BN], cluS[BN], rowGt[BQ], rowClu[BQ];

    const int tid = threadIdx.x;
    const int jb  = blockIdx.x;
    const int j0  = jb * BN;

    if (tid < BN) {
        int jg = j0 + tid;
        int jc = jg < NBANK ? jg : NBANK - 1;
        clsS[tid] = class_label[jc];
        cluS[tid] = cluster_label[jc];
    }
    rowGt[tid]  = gt_label[tid];
    rowClu[tid] = cluster_idx[tid];

    // Staging role: col = tid>>2 (0..63), q = tid&2bits -> k-octet q*8..+7 of the slice
    const int col = tid >> 2, q = tid & 3;
    const int ct_s = col >> 4, cl_s = col & 15;
    const int wi   = ct_s * 64 + q * 16 + cl_s;        // frag-lane index in LDS
    {
        int jcol = j0 + col;
        jcol = jcol < NBANK ? jcol : NBANK - 1;
        const float* gb = bank + (size_t)jcol * DDIM + q * 8;

        // Compute role: wave w, lane; g = k-octet / row-quad, c = col-in-tile
        const int w = tid >> 6, lane = tid & 63;
        const int g = lane >> 4, c = lane & 15;

        f32x4 acc[4][4];
        #pragma unroll
        for (int ct = 0; ct < 4; ++ct)
            #pragma unroll
            for (int rt = 0; rt < 4; ++rt)
                acc[ct][rt] = (f32x4){0.f, 0.f, 0.f, 0.f};
        float sqa = 0.f;

        float4 cur0 = *(const float4*)(gb);
        float4 cur1 = *(const float4*)(gb + 4);

        for (int s = 0; s < 8; ++s) {
            // A frags for this slice (L2-resident, fragment-ordered): issue early
            s8 aHr[4], aLr[4];
            #pragma unroll
            for (int rt = 0; rt < 4; ++rt) {
                const int RT = w * 4 + rt;
                aHr[rt] = fH[(RT * 8 + s) * 64 + lane];
                aLr[rt] = fL[(RT * 8 + s) * 64 + lane];
            }
            __syncthreads();               // prior compute's ds_reads complete
            {
                s8 h, l;
                split8(cur0, cur1, h, l);
                sqa = sq8(cur0, cur1, sqa);
                bHs[wi] = h;               // per-lane contiguous 16B: conflict-free
                bLs[wi] = l;
            }
            __syncthreads();               // staging visible
            if (s < 7) {                   // prefetch next slice (overlaps compute)
                cur0 = *(const float4*)(gb + (s + 1) * 32);
                cur1 = *(const float4*)(gb + (s + 1) * 32 + 4);
            }
            #pragma unroll
            for (int ct = 0; ct < 4; ++ct) {
                const s8 bh = bHs[ct * 64 + lane];
                const s8 bl = bLs[ct * 64 + lane];
                #pragma unroll
                for (int rt = 0; rt < 4; ++rt) {
                    acc[ct][rt] = __builtin_amdgcn_mfma_f32_16x16x32_bf16(aHr[rt], bh, acc[ct][rt], 0, 0, 0);
                    acc[ct][rt] = __builtin_amdgcn_mfma_f32_16x16x32_bf16(aHr[rt], bl, acc[ct][rt], 0, 0, 0);
                    acc[ct][rt] = __builtin_amdgcn_mfma_f32_16x16x32_bf16(aLr[rt], bh, acc[ct][rt], 0, 0, 0);
                    acc[ct][rt] = __builtin_amdgcn_mfma_f32_16x16x32_bf16(aLr[rt], bl, acc[ct][rt], 0, 0, 0);
                }
            }
        }

        // ||b||^2: the 4 q-threads of each col are adjacent lanes
        sqa += __shfl_xor(sqa, 1);
        sqa += __shfl_xor(sqa, 2);
        if (q == 0) b2s[col] = sqa;
        __syncthreads();

        // Epilogue: C/D layout col = lane&15, row = g*4 + reg (HW-verified R3, absmax 0)
        #pragma unroll
        for (int rt = 0; rt < 4; ++rt) {
            #pragma unroll
            for (int r = 0; r < 4; ++r) {
                const int row  = w * 64 + rt * 16 + g * 4 + r;
                const int myGt = rowGt[row], myClu = rowClu[row];
                float bpv = SENT, bdv = SENT;
                int   bpi = INT_MAX, bdi = INT_MAX;
                #pragma unroll
                for (int ct = 0; ct < 4; ++ct) {   // ascending ct = ascending col per lane
                    const int jg = j0 + ct * 16 + c;
                    const float sc = b2s[ct * 16 + c] - 2.f * acc[ct][rt][r];
                    if (jg < NBANK && clsS[ct * 16 + c] != myGt) {
                        if (sc < bdv) { bdv = sc; bdi = jg; }
                        if (cluS[ct * 16 + c] == myClu && sc < bpv) { bpv = sc; bpi = jg; }
                    }
                }
                #pragma unroll
                for (int off = 1; off < 16; off <<= 1) {   // tie-aware 16-lane reduce
                    float vv = __shfl_xor(bpv, off); int ii = __shfl_xor(bpi, off);
                    if (vv < bpv || (vv == bpv && ii < bpi)) { bpv = vv; bpi = ii; }
                    vv = __shfl_xor(bdv, off); ii = __shfl_xor(bdi, off);
                    if (vv < bdv || (vv == bdv && ii < bdi)) { bdv = vv; bdi = ii; }
                }
                if (c == 0) {
                    const size_t o = (size_t)row * NJB + jb;
                    wsPV[o] = bpv; wsPI[o] = bpi;
                    wsDV[o] = bdv; wsDI[o] = bdi;
                }
            }
        }
    }
}

// Kernel 2: per-row reduction over NJB partials, fallback select, gather bank row.
__global__ __launch_bounds__(256) void reduce_gather(
    const float* __restrict__ wsPV, const int* __restrict__ wsPI,
    const float* __restrict__ wsDV, const int* __restrict__ wsDI,
    const float* __restrict__ bank, float* __restrict__ out)
{
    const int row = blockIdx.x, tid = threadIdx.x;
    float bpv = SENT, bdv = SENT;
    int   bpi = INT_MAX, bdi = INT_MAX;
    for (int b = tid; b < NJB; b += 256) {
        float v = wsPV[(size_t)row * NJB + b]; int ix = wsPI[(size_t)row * NJB + b];
        if (v < bpv || (v == bpv && ix < bpi)) { bpv = v; bpi = ix; }
        v = wsDV[(size_t)row * NJB + b]; ix = wsDI[(size_t)row * NJB + b];
        if (v < bdv || (v == bdv && ix < bdi)) { bdv = v; bdi = ix; }
    }
    #pragma unroll
    for (int off = 32; off > 0; off >>= 1) {
        float v = __shfl_down(bpv, off); int ix = __shfl_down(bpi, off);
        if (v < bpv || (v == bpv && ix < bpi)) { bpv = v; bpi = ix; }
        v = __shfl_down(bdv, off); ix = __shfl_down(bdi, off);
        if (v < bdv || (v == bdv && ix < bdi)) { bdv = v; bdi = ix; }
    }
    __shared__ float swPV[4], swDV[4];
    __shared__ int   swPI[4], swDI[4];
    __shared__ int   sIdx;
    const int lane = tid & 63, wv = tid >> 6;
    if (lane == 0) { swPV[wv] = bpv; swPI[wv] = bpi; swDV[wv] = bdv; swDI[wv] = bdi; }
    __syncthreads();
    if (tid == 0) {
        float pv = swPV[0]; int pi = swPI[0];
        float dv = swDV[0]; int di = swDI[0];
        #pragma unroll
        for (int w = 1; w < 4; ++w) {
            if (swPV[w] < pv || (swPV[w] == pv && swPI[w] < pi)) { pv = swPV[w]; pi = swPI[w]; }
            if (swDV[w] < dv || (swDV[w] == dv && swDI[w] < di)) { dv = swDV[w]; di = swDI[w]; }
        }
        sIdx = (pi != INT_MAX) ? pi : ((di != INT_MAX) ? di : 0);
    }
    __syncthreads();
    out[row * DDIM + tid] = bank[(size_t)sIdx * DDIM + tid];
}

extern "C" void kernel_launch(void* const* d_in, const int* in_sizes, int n_in,
                              void* d_out, int out_size, void* d_ws, size_t ws_size,
                              hipStream_t stream) {
    const float* feature       = (const float*)d_in[0];
    const float* bank          = (const float*)d_in[1];
    const int*   cluster_label = (const int*)d_in[2];
    const int*   class_label   = (const int*)d_in[3];
    const int*   cluster_idx   = (const int*)d_in[4];
    const int*   gt_label      = (const int*)d_in[5];
    float* out = (float*)d_out;

    // Workspace: fH/fL (128 KB each) + 4 partial arrays [256][NJB] (6.4 MB) = 6.66 MB
    s8* fH = (s8*)d_ws;                 // 8192 frags
    s8* fL = fH + 8192;
    float* base = (float*)((char*)d_ws + 2 * 8192 * sizeof(s8));
    const size_t per = (size_t)BQ * NJB;
    float* wsPV = base;
    int*   wsPI = (int*)base + per;
    float* wsDV = base + 2 * per;
    int*   wsDI = (int*)base + 3 * per;

    hipLaunchKernelGGL(split_feature, dim3(16), dim3(512), 0, stream, feature, fH, fL);
    hipLaunchKernelGGL(gemm_argmin_partial, dim3(NJB), dim3(256), 0, stream,
                       fH, fL, bank, cluster_label, class_label, cluster_idx, gt_label,
                       wsPV, wsPI, wsDV, wsDI);
    hipLaunchKernelGGL(reduce_gather, dim3(BQ), dim3(256), 0, stream,
                       wsPV, wsPI, wsDV, wsDI, bank, out);
}